// Round 8
// baseline (447.334 us; speedup 1.0000x reference)
//
#include <hip/hip_runtime.h>
#include <hip/hip_bf16.h>
#include <math.h>

#define B_    32
#define NIN_  2312
#define NHID_ 512
#define NOUT_ 10
#define T_    350
#define KLEN  77      // truncated SRM alpha kernel length (taps 0..76)
#define MW    40      // u64 words per (b,t) input mask row (37 used, padded)
#define NIB   37      // ceil(NIN/64)
#define NTC   22      // ceil(T/16)
#define MAXA2 320     // max active inputs per (b,t); Binom(2312,0.03) max ~110

// ---------------- W1 transpose: W1[o][i] -> W1T[i][o] ----------------
__global__ __launch_bounds__(256) void w1t_k(const float* __restrict__ W,
                                             float* __restrict__ WT) {
  __shared__ float tile[32][33];
  int i0 = blockIdx.x * 32, o0 = blockIdx.y * 32;
  int tx = threadIdx.x, tyb = threadIdx.y;
#pragma unroll
  for (int s = 0; s < 4; ++s) {
    int ty = tyb + s * 8;
    int o = o0 + ty, i = i0 + tx;
    if (i < NIN_) tile[ty][tx] = W[(size_t)o * NIN_ + i];
  }
  __syncthreads();
#pragma unroll
  for (int s = 0; s < 4; ++s) {
    int ty = tyb + s * 8;
    int i = i0 + ty, o = o0 + tx;
    if (i < NIN_) WT[(size_t)i * NHID_ + o] = tile[tx][ty];
  }
}

// ------------- input bitmask via ballot-transpose: NO atomics, no memset -------------
// wave owns (b, 64-i block, 16-t chunk); lane = i. NO local array anywhere:
// 8 NAMED float2 registers + a macro-expanded fully-static ballot sequence.
// (Rounds 5/6 lesson: any alloca reachable by a runtime index — including a
// loop that fails to unroll because of `break` — gets demoted to LDS by
// AMDGPUPromoteAlloca and becomes a 32-way bank-conflict disaster.)
__global__ __launch_bounds__(256) void inmask_k(const float* __restrict__ X,
                                                unsigned long long* __restrict__ msk) {
  int w = blockIdx.x * 4 + (threadIdx.x >> 6);
  int lane = threadIdx.x & 63;
  if (w >= B_ * NIB * NTC) return;
  int b = w / (NIB * NTC);
  int rem = w - b * (NIB * NTC);
  int iblk = rem / NTC, tc = rem - iblk * NTC;
  int i = iblk * 64 + lane;
  int t0 = tc * 16;
  int nk = (t0 + 16 <= T_) ? 16 : (T_ - t0);      // wave-uniform; T_=350 -> tail nk=14 (even)
  int nw = nk >> 1;
  bool valid = (i < NIN_);
  const float2* rp = (const float2*)(X + ((size_t)b * NIN_ + (valid ? i : 0)) * T_ + t0);
  const float2 zz = make_float2(0.f, 0.f);
  float2 v0 = (valid && 0 < nw) ? rp[0] : zz;
  float2 v1 = (valid && 1 < nw) ? rp[1] : zz;
  float2 v2 = (valid && 2 < nw) ? rp[2] : zz;
  float2 v3 = (valid && 3 < nw) ? rp[3] : zz;
  float2 v4 = (valid && 4 < nw) ? rp[4] : zz;
  float2 v5 = (valid && 5 < nw) ? rp[5] : zz;
  float2 v6 = (valid && 6 < nw) ? rp[6] : zz;
  float2 v7 = (valid && 7 < nw) ? rp[7] : zz;
  unsigned long long* mrow = msk + ((size_t)b * T_ + t0) * MW + iblk;
  // All 16 ballots execute unconditionally (wave-uniform); tail ballots are
  // computed on zeros and simply not stored (k < nk store predicate).
#define BAL_(K, COMP)                                                          \
  {                                                                            \
    unsigned long long bw_ = __ballot((COMP) != 0.0f);                         \
    if ((K) < nk && lane == (K)) mrow[(size_t)(K) * MW] = bw_;                 \
  }
  BAL_(0,  v0.x) BAL_(1,  v0.y) BAL_(2,  v1.x) BAL_(3,  v1.y)
  BAL_(4,  v2.x) BAL_(5,  v2.y) BAL_(6,  v3.x) BAL_(7,  v3.y)
  BAL_(8,  v4.x) BAL_(9,  v4.y) BAL_(10, v5.x) BAL_(11, v5.y)
  BAL_(12, v6.x) BAL_(13, v6.y) BAL_(14, v7.x) BAL_(15, v7.y)
#undef BAL_
}

// ------------- sparse accumulate: Z1[b][t][o] = sum_{active i, ascending} W1T[i][o] -------------
// One 64-thread block per (b,t,o-half-of-256). float4 gathers (1 KB/wave-inst).
// Each output column sums in strict ascending-i serial order -> bit-identical
// to prior rounds.
__global__ __launch_bounds__(64) void accum1_k(const unsigned long long* __restrict__ msk,
                                               const float* __restrict__ WT,
                                               float* __restrict__ Z1) {
  __shared__ unsigned short list[MAXA2];
  int id = blockIdx.x;
  int bt = id >> 1, oc = id & 1;
  int lane = threadIdx.x;
  unsigned long long wm = (lane < NIB) ? msk[(size_t)bt * MW + lane] : 0ull;
  int pc = __popcll(wm);
  int pre = pc;
#pragma unroll
  for (int d = 1; d < 64; d <<= 1) {
    int o = __shfl_up(pre, d);
    if (lane >= d) pre += o;
  }
  int base = pre - pc;                  // exclusive prefix
  int n = __shfl(pre, 63);              // total actives
  while (wm) {
    int j = __builtin_ctzll(wm);
    if (base < MAXA2) list[base] = (unsigned short)(lane * 64 + j);
    ++base;
    wm &= wm - 1;
  }
  __syncthreads();
  if (n > MAXA2) n = MAXA2;
  const float4* wbase = (const float4*)WT + (size_t)oc * 64 + lane;  // float4 units
  float4 acc = make_float4(0.f, 0.f, 0.f, 0.f);
#pragma unroll 8
  for (int j = 0; j < n; ++j) {
    float4 v = wbase[(size_t)list[j] * (NHID_ / 4)];
    acc.x += v.x;                       // strict ascending-i order per output column
    acc.y += v.y;
    acc.z += v.z;
    acc.w += v.w;
  }
  ((float4*)(Z1 + (size_t)bt * NHID_))[(size_t)oc * 64 + lane] = acc;
}

// ------------- layer-1 scan: truncated-PSP dual IIR (fp64) + refractory (fp32) -------------
__global__ __launch_bounds__(64) void scan1_k(const float* __restrict__ Z1,
                                              unsigned long long* __restrict__ mask) {
  int lane = threadIdx.x;
  int b = blockIdx.x >> 3, g = blockIdx.x & 7;
  int h = g * 64 + lane;
  const double dp   = exp(-0.1);            // PSP decay per step
  const double Ap   = exp(1.0) / 10.0;      // kernel scale (e/tau) x Ts
  const double D77  = exp(-7.7);            // dp^77
  const float  Dref = (float)exp(-1.0);
  const float  Cref = (float)(-20.0 * exp(1.0));  // -SCALE_REF*THETA*e*Ts/TAU_REF
  double Xc = 0.0, Yc = 0.0, Xd = 0.0, Yd = 0.0;
  float xr = 0.f, yr = 0.f;
  const float* zb = Z1 + (size_t)b * T_ * NHID_ + h;
  unsigned long long* mb = mask + (size_t)b * T_ * 8 + g;
  for (int t0 = 0; t0 < T_; t0 += 16) {
    float z[16], zd[16];
#pragma unroll
    for (int k = 0; k < 16; ++k) {
      int t = t0 + k;
      z[k]  = (t < T_) ? zb[(size_t)t * NHID_] : 0.f;
      zd[k] = (t >= KLEN && t < T_) ? zb[(size_t)(t - KLEN) * NHID_] : 0.f;
    }
#pragma unroll
    for (int k = 0; k < 16; ++k) {
      int t = t0 + k;
      if (t >= T_) break;                 // uniform
      Yc = dp * (Yc + Xc); Xc = dp * Xc + (double)z[k];
      Yd = dp * (Yd + Xd); Xd = dp * Xd + (double)zd[k];
      float p = (float)(Ap * (Yc - D77 * (Yd + 77.0 * Xd)));
      yr = Dref * (yr + xr);
      float u = p + Cref * yr;
      float s = (u >= 10.0f) ? 1.0f : 0.0f;
      xr = Dref * xr + s;
      unsigned long long bw = __ballot(u >= 10.0f);
      if (lane == 0) mb[(size_t)t * 8] = bw;
    }
  }
}

// ------------- layer-2 GEMM via spike bitmask: Z2[b][o][t] = sum_{h set, ascending} W2[o][h] -------------
__global__ __launch_bounds__(256) void z2_k(const unsigned long long* __restrict__ mask,
                                            const float* __restrict__ W2,
                                            float* __restrict__ Z2) {
  int wave = blockIdx.x * 4 + (threadIdx.x >> 6);
  int lane = threadIdx.x & 63;
  if (wave >= B_ * T_) return;
  int b = wave / T_, t = wave - b * T_;
  const unsigned long long* m = mask + (size_t)wave * 8;
  if (lane < NOUT_) {
    const float* wr = W2 + (size_t)lane * NHID_;
    float acc = 0.f;
#pragma unroll
    for (int w = 0; w < 8; ++w) {
      unsigned long long mm = m[w];
      while (mm) {
        int j = __builtin_ctzll(mm);
        mm &= mm - 1;
        acc += wr[w * 64 + j];
      }
    }
    Z2[((size_t)b * NOUT_ + lane) * T_ + t] = acc;
  }
}

// ------------- layer-2 scan -> output spikes (16-deep prefetch) -------------
__global__ __launch_bounds__(64) void scan2_k(const float* __restrict__ Z2,
                                              float* __restrict__ out) {
  int n = blockIdx.x * 64 + threadIdx.x;    // n = b*NOUT + o
  if (n >= B_ * NOUT_) return;
  const double dp   = exp(-0.1);
  const double Ap   = exp(1.0) / 10.0;
  const double D77  = exp(-7.7);
  const float  Dref = (float)exp(-1.0);
  const float  Cref = (float)(-20.0 * exp(1.0));
  double Xc = 0.0, Yc = 0.0, Xd = 0.0, Yd = 0.0;
  float xr = 0.f, yr = 0.f;
  const float* row = Z2 + (size_t)n * T_;
  float* orow = out + (size_t)n * T_;
  for (int t0 = 0; t0 < T_; t0 += 16) {
    float z[16], zd[16];
#pragma unroll
    for (int k = 0; k < 16; ++k) {
      int t = t0 + k;
      z[k]  = (t < T_) ? row[t] : 0.f;
      zd[k] = (t >= KLEN && t < T_) ? row[t - KLEN] : 0.f;
    }
#pragma unroll
    for (int k = 0; k < 16; ++k) {
      int t = t0 + k;
      if (t >= T_) break;                 // uniform
      Yc = dp * (Yc + Xc); Xc = dp * Xc + (double)z[k];
      Yd = dp * (Yd + Xd); Xd = dp * Xd + (double)zd[k];
      float p = (float)(Ap * (Yc - D77 * (Yd + 77.0 * Xd)));
      yr = Dref * (yr + xr);
      float u = p + Cref * yr;
      float s = (u >= 10.0f) ? 1.0f : 0.0f;
      xr = Dref * xr + s;
      orow[t] = s;   // spk / Ts, Ts = 1
    }
  }
}

extern "C" void kernel_launch(void* const* d_in, const int* in_sizes, int n_in,
                              void* d_out, int out_size, void* d_ws, size_t ws_size,
                              hipStream_t stream) {
  const float* X  = (const float*)d_in[0];  // (32, 2312, 350)
  const float* W1 = (const float*)d_in[1];  // (512, 2312)
  const float* W2 = (const float*)d_in[2];  // (10, 512)
  float* out = (float*)d_out;               // (32, 10, 350)

  char* ws = (char*)d_ws;
  size_t off = 0;
  float* W1T = (float*)(ws + off);                 off += (size_t)NIN_ * NHID_ * 4;         // 4.73 MB
  unsigned long long* msk = (unsigned long long*)(ws + off); off += (size_t)B_ * T_ * MW * 8; // 3.58 MB
  float* Z1 = (float*)(ws + off);                  off += (size_t)B_ * T_ * NHID_ * 4;      // 22.9 MB
  unsigned long long* mask = (unsigned long long*)(ws + off); off += (size_t)B_ * T_ * 8 * 8; // 0.72 MB
  float* Z2 = (float*)(ws + off);                  off += (size_t)B_ * NOUT_ * T_ * 4;      // 0.45 MB
  if (off > ws_size) return;  // workspace too small -> fail loudly (no launches)

  w1t_k<<<dim3((NIN_ + 31) / 32, NHID_ / 32), dim3(32, 8), 0, stream>>>(W1, W1T);
  inmask_k<<<(B_ * NIB * NTC + 3) / 4, 256, 0, stream>>>(X, msk);
  accum1_k<<<B_ * T_ * 2, 64, 0, stream>>>(msk, W1T, Z1);
  scan1_k<<<B_ * 8, 64, 0, stream>>>(Z1, mask);
  z2_k<<<(B_ * T_ + 3) / 4, 256, 0, stream>>>(mask, W2, Z2);
  scan2_k<<<(B_ * NOUT_ + 63) / 64, 64, 0, stream>>>(Z2, out);
}

// Round 9
// 385.841 us; speedup vs baseline: 1.1594x; 1.1594x over previous
//
#include <hip/hip_runtime.h>
#include <hip/hip_bf16.h>
#include <math.h>

#define B_    32
#define NIN_  2312
#define NHID_ 512
#define NOUT_ 10
#define T_    350
#define KLEN  77      // truncated SRM alpha kernel length (taps 0..76)
#define MW    40      // u64 words per (b,t) input mask row (37 used, padded)
#define NIB   37      // ceil(NIN/64)
#define NTB   6       // ceil(T/64) t-chunks per row for inmask tiling
#define MAXA2 320     // max active inputs per (b,t); Binom(2312,0.03) max ~110

// ---------------- W1 transpose: W1[o][i] -> W1T[i][o] ----------------
__global__ __launch_bounds__(256) void w1t_k(const float* __restrict__ W,
                                             float* __restrict__ WT) {
  __shared__ float tile[32][33];
  int i0 = blockIdx.x * 32, o0 = blockIdx.y * 32;
  int tx = threadIdx.x, tyb = threadIdx.y;
#pragma unroll
  for (int s = 0; s < 4; ++s) {
    int ty = tyb + s * 8;
    int o = o0 + ty, i = i0 + tx;
    if (i < NIN_) tile[ty][tx] = W[(size_t)o * NIN_ + i];
  }
  __syncthreads();
#pragma unroll
  for (int s = 0; s < 4; ++s) {
    int ty = tyb + s * 8;
    int i = i0 + ty, o = o0 + tx;
    if (i < NIN_) WT[(size_t)i * NHID_ + o] = tile[tx][ty];
  }
}

// ------------- input bitmask: coalesced tile read + LDS bit-transpose -------------
// Block = (b, 64-i block, 64-t chunk), 256 threads. Phase 1: thread (r=tid>>2,
// c=tid&3) reads 16 consecutive t of row r as 8 predicated float2 (4 threads
// cover a full 64B line, 8 a 128B line -> each HBM line fetched once, fully
// used; round-8's per-lane-row pattern over-fetched 3x). Reduce to a 16-bit
// nonzero mask in LDS. Phase 2: wave w takes t-subchunk w; lane reads
// bits[lane][w]; 16 static ballots produce the mask words (wave-exclusive ->
// plain stores). No alloca anywhere (rounds 5/6 LDS-demotion lesson).
__global__ __launch_bounds__(256) void inmask_k(const float* __restrict__ X,
                                                unsigned long long* __restrict__ msk) {
  __shared__ unsigned short bits[64][4];
  int blk = blockIdx.x;
  int tb = blk % NTB;
  int rem = blk / NTB;
  int iblk = rem % NIB;
  int b = rem / NIB;
  int tid = threadIdx.x;
  int r = tid >> 2, c = tid & 3;
  int i = iblk * 64 + r;
  int tbase = tb * 64 + c * 16;
  bool rowok = (i < NIN_);
  const float2* rp = (const float2*)(X + ((size_t)b * NIN_ + (rowok ? i : 0)) * T_ + tbase);
  unsigned m = 0;
#define LD_(Q)                                                                 \
  {                                                                            \
    float2 vq = (rowok && (tbase + 2 * (Q) + 1) < T_) ? rp[Q]                  \
                                                      : make_float2(0.f, 0.f); \
    m |= (vq.x != 0.f ? 1u : 0u) << (2 * (Q));                                 \
    m |= (vq.y != 0.f ? 1u : 0u) << (2 * (Q) + 1);                             \
  }
  LD_(0) LD_(1) LD_(2) LD_(3) LD_(4) LD_(5) LD_(6) LD_(7)
#undef LD_
  bits[r][c] = (unsigned short)m;
  __syncthreads();
  int w = tid >> 6, lane = tid & 63;
  unsigned bm = bits[lane][w];
  unsigned long long* mrow = msk + ((size_t)b * T_ + (size_t)tb * 64 + w * 16) * MW + iblk;
  int tb16 = tb * 64 + w * 16;
#define BAL_(P)                                                                \
  {                                                                            \
    unsigned long long bw_ = __ballot(((bm >> (P)) & 1u) != 0u);               \
    if ((tb16 + (P)) < T_ && lane == (P)) mrow[(size_t)(P) * MW] = bw_;        \
  }
  BAL_(0)  BAL_(1)  BAL_(2)  BAL_(3)  BAL_(4)  BAL_(5)  BAL_(6)  BAL_(7)
  BAL_(8)  BAL_(9)  BAL_(10) BAL_(11) BAL_(12) BAL_(13) BAL_(14) BAL_(15)
#undef BAL_
}

// ------------- sparse accumulate: Z1[b][t][o] = sum_{active i, ascending} W1T[i][o] -------------
// One 64-thread block per (b,t,o-half-of-256). float4 gathers (1 KB/wave-inst).
// Each output column sums in strict ascending-i serial order -> bit-identical
// to prior rounds.
__global__ __launch_bounds__(64) void accum1_k(const unsigned long long* __restrict__ msk,
                                               const float* __restrict__ WT,
                                               float* __restrict__ Z1) {
  __shared__ unsigned short list[MAXA2];
  int id = blockIdx.x;
  int bt = id >> 1, oc = id & 1;
  int lane = threadIdx.x;
  unsigned long long wm = (lane < NIB) ? msk[(size_t)bt * MW + lane] : 0ull;
  int pc = __popcll(wm);
  int pre = pc;
#pragma unroll
  for (int d = 1; d < 64; d <<= 1) {
    int o = __shfl_up(pre, d);
    if (lane >= d) pre += o;
  }
  int base = pre - pc;                  // exclusive prefix
  int n = __shfl(pre, 63);              // total actives
  while (wm) {
    int j = __builtin_ctzll(wm);
    if (base < MAXA2) list[base] = (unsigned short)(lane * 64 + j);
    ++base;
    wm &= wm - 1;
  }
  __syncthreads();
  if (n > MAXA2) n = MAXA2;
  const float4* wbase = (const float4*)WT + (size_t)oc * 64 + lane;  // float4 units
  float4 acc = make_float4(0.f, 0.f, 0.f, 0.f);
#pragma unroll 8
  for (int j = 0; j < n; ++j) {
    float4 v = wbase[(size_t)list[j] * (NHID_ / 4)];
    acc.x += v.x;                       // strict ascending-i order per output column
    acc.y += v.y;
    acc.z += v.z;
    acc.w += v.w;
  }
  ((float4*)(Z1 + (size_t)bt * NHID_))[(size_t)oc * 64 + lane] = acc;
}

// ------------- layer-1 scan: truncated-PSP dual IIR (fp64) + refractory (fp32) -------------
__global__ __launch_bounds__(64) void scan1_k(const float* __restrict__ Z1,
                                              unsigned long long* __restrict__ mask) {
  int lane = threadIdx.x;
  int b = blockIdx.x >> 3, g = blockIdx.x & 7;
  int h = g * 64 + lane;
  const double dp   = exp(-0.1);            // PSP decay per step
  const double Ap   = exp(1.0) / 10.0;      // kernel scale (e/tau) x Ts
  const double D77  = exp(-7.7);            // dp^77
  const float  Dref = (float)exp(-1.0);
  const float  Cref = (float)(-20.0 * exp(1.0));  // -SCALE_REF*THETA*e*Ts/TAU_REF
  double Xc = 0.0, Yc = 0.0, Xd = 0.0, Yd = 0.0;
  float xr = 0.f, yr = 0.f;
  const float* zb = Z1 + (size_t)b * T_ * NHID_ + h;
  unsigned long long* mb = mask + (size_t)b * T_ * 8 + g;
  for (int t0 = 0; t0 < T_; t0 += 16) {
    float z[16], zd[16];
#pragma unroll
    for (int k = 0; k < 16; ++k) {
      int t = t0 + k;
      z[k]  = (t < T_) ? zb[(size_t)t * NHID_] : 0.f;
      zd[k] = (t >= KLEN && t < T_) ? zb[(size_t)(t - KLEN) * NHID_] : 0.f;
    }
#pragma unroll
    for (int k = 0; k < 16; ++k) {
      int t = t0 + k;
      if (t >= T_) break;                 // uniform
      Yc = dp * (Yc + Xc); Xc = dp * Xc + (double)z[k];
      Yd = dp * (Yd + Xd); Xd = dp * Xd + (double)zd[k];
      float p = (float)(Ap * (Yc - D77 * (Yd + 77.0 * Xd)));
      yr = Dref * (yr + xr);
      float u = p + Cref * yr;
      float s = (u >= 10.0f) ? 1.0f : 0.0f;
      xr = Dref * xr + s;
      unsigned long long bw = __ballot(u >= 10.0f);
      if (lane == 0) mb[(size_t)t * 8] = bw;
    }
  }
}

// ------------- layer-2 GEMM via spike bitmask: Z2[b][o][t] = sum_{h set, ascending} W2[o][h] -------------
__global__ __launch_bounds__(256) void z2_k(const unsigned long long* __restrict__ mask,
                                            const float* __restrict__ W2,
                                            float* __restrict__ Z2) {
  int wave = blockIdx.x * 4 + (threadIdx.x >> 6);
  int lane = threadIdx.x & 63;
  if (wave >= B_ * T_) return;
  int b = wave / T_, t = wave - b * T_;
  const unsigned long long* m = mask + (size_t)wave * 8;
  if (lane < NOUT_) {
    const float* wr = W2 + (size_t)lane * NHID_;
    float acc = 0.f;
#pragma unroll
    for (int w = 0; w < 8; ++w) {
      unsigned long long mm = m[w];
      while (mm) {
        int j = __builtin_ctzll(mm);
        mm &= mm - 1;
        acc += wr[w * 64 + j];
      }
    }
    Z2[((size_t)b * NOUT_ + lane) * T_ + t] = acc;
  }
}

// ------------- layer-2 scan -> output spikes (16-deep prefetch) -------------
__global__ __launch_bounds__(64) void scan2_k(const float* __restrict__ Z2,
                                              float* __restrict__ out) {
  int n = blockIdx.x * 64 + threadIdx.x;    // n = b*NOUT + o
  if (n >= B_ * NOUT_) return;
  const double dp   = exp(-0.1);
  const double Ap   = exp(1.0) / 10.0;
  const double D77  = exp(-7.7);
  const float  Dref = (float)exp(-1.0);
  const float  Cref = (float)(-20.0 * exp(1.0));
  double Xc = 0.0, Yc = 0.0, Xd = 0.0, Yd = 0.0;
  float xr = 0.f, yr = 0.f;
  const float* row = Z2 + (size_t)n * T_;
  float* orow = out + (size_t)n * T_;
  for (int t0 = 0; t0 < T_; t0 += 16) {
    float z[16], zd[16];
#pragma unroll
    for (int k = 0; k < 16; ++k) {
      int t = t0 + k;
      z[k]  = (t < T_) ? row[t] : 0.f;
      zd[k] = (t >= KLEN && t < T_) ? row[t - KLEN] : 0.f;
    }
#pragma unroll
    for (int k = 0; k < 16; ++k) {
      int t = t0 + k;
      if (t >= T_) break;                 // uniform
      Yc = dp * (Yc + Xc); Xc = dp * Xc + (double)z[k];
      Yd = dp * (Yd + Xd); Xd = dp * Xd + (double)zd[k];
      float p = (float)(Ap * (Yc - D77 * (Yd + 77.0 * Xd)));
      yr = Dref * (yr + xr);
      float u = p + Cref * yr;
      float s = (u >= 10.0f) ? 1.0f : 0.0f;
      xr = Dref * xr + s;
      orow[t] = s;   // spk / Ts, Ts = 1
    }
  }
}

extern "C" void kernel_launch(void* const* d_in, const int* in_sizes, int n_in,
                              void* d_out, int out_size, void* d_ws, size_t ws_size,
                              hipStream_t stream) {
  const float* X  = (const float*)d_in[0];  // (32, 2312, 350)
  const float* W1 = (const float*)d_in[1];  // (512, 2312)
  const float* W2 = (const float*)d_in[2];  // (10, 512)
  float* out = (float*)d_out;               // (32, 10, 350)

  char* ws = (char*)d_ws;
  size_t off = 0;
  float* W1T = (float*)(ws + off);                 off += (size_t)NIN_ * NHID_ * 4;         // 4.73 MB
  unsigned long long* msk = (unsigned long long*)(ws + off); off += (size_t)B_ * T_ * MW * 8; // 3.58 MB
  float* Z1 = (float*)(ws + off);                  off += (size_t)B_ * T_ * NHID_ * 4;      // 22.9 MB
  unsigned long long* mask = (unsigned long long*)(ws + off); off += (size_t)B_ * T_ * 8 * 8; // 0.72 MB
  float* Z2 = (float*)(ws + off);                  off += (size_t)B_ * NOUT_ * T_ * 4;      // 0.45 MB
  if (off > ws_size) return;  // workspace too small -> fail loudly (no launches)

  w1t_k<<<dim3((NIN_ + 31) / 32, NHID_ / 32), dim3(32, 8), 0, stream>>>(W1, W1T);
  inmask_k<<<B_ * NIB * NTB, 256, 0, stream>>>(X, msk);
  accum1_k<<<B_ * T_ * 2, 64, 0, stream>>>(msk, W1T, Z1);
  scan1_k<<<B_ * 8, 64, 0, stream>>>(Z1, mask);
  z2_k<<<(B_ * T_ + 3) / 4, 256, 0, stream>>>(mask, W2, Z2);
  scan2_k<<<(B_ * NOUT_ + 63) / 64, 64, 0, stream>>>(Z2, out);
}

// Round 10
// 354.705 us; speedup vs baseline: 1.2611x; 1.0878x over previous
//
#include <hip/hip_runtime.h>
#include <hip/hip_bf16.h>
#include <math.h>

#define B_    32
#define NIN_  2312
#define NHID_ 512
#define NOUT_ 10
#define T_    350
#define KLEN  77      // truncated SRM alpha kernel length (taps 0..76)
#define MW    40      // u64 words per (b,t) input mask row (37 used, padded)
#define NIB   37      // ceil(NIN/64)
#define NTB   6       // 64-t chunks per row
#define MAXA2 320     // max active inputs per (b,t); Binom(2312,0.03) max ~110

// ---------------- W1 transpose: W1[o][i] -> W1T[i][o] ----------------
__global__ __launch_bounds__(256) void w1t_k(const float* __restrict__ W,
                                             float* __restrict__ WT) {
  __shared__ float tile[32][33];
  int i0 = blockIdx.x * 32, o0 = blockIdx.y * 32;
  int tx = threadIdx.x, tyb = threadIdx.y;
#pragma unroll
  for (int s = 0; s < 4; ++s) {
    int ty = tyb + s * 8;
    int o = o0 + ty, i = i0 + tx;
    if (i < NIN_) tile[ty][tx] = W[(size_t)o * NIN_ + i];
  }
  __syncthreads();
#pragma unroll
  for (int s = 0; s < 4; ++s) {
    int ty = tyb + s * 8;
    int i = i0 + ty, o = o0 + tx;
    if (i < NIN_) WT[(size_t)i * NHID_ + o] = tile[tx][ty];
  }
}

// ------------- input bitmask v3: per-INSTRUCTION-contiguous loads + dual-ballot pack -------------
// Block = (b, 64-i block); loops over six 64-t chunks (row-boundary lines stay
// in L1). Phase 1: wave w, step q loads rows 16w+2q / +1 — lanes 0-31 cover row
// A's 256B span, lanes 32-63 row B's: each INSTRUCTION reads 2x256B contiguous
// (~5 lines) vs round-9's 40 lines/inst. ballot(v.x!=0)/ballot(v.y!=0) directly
// yield the even-t/odd-t 32-bit masks of both rows -> 2 lanes store them to a
// 512B LDS array. Phase 2: lane=row re-ballots -> i-mask words (wave-exclusive
// stores). No local arrays anywhere (rounds 5/6 LDS-demotion lesson).
__global__ __launch_bounds__(256) void inmask_k(const float* __restrict__ X,
                                                unsigned long long* __restrict__ msk) {
  __shared__ unsigned evens[64], odds[64];
  int blk = blockIdx.x;
  int iblk = blk % NIB;
  int b = blk / NIB;
  int tid = threadIdx.x;
  int w = tid >> 6, lane = tid & 63;
  int rhalf = lane >> 5;           // which row of the pair
  int c2 = lane & 31;              // float2 column within the 64-t chunk
  const float* base = X + ((size_t)b * NIN_ + (size_t)iblk * 64) * T_;
  for (int tb = 0; tb < NTB; ++tb) {
    int tbase = tb * 64;
#define PH1_(Q)                                                                \
  {                                                                            \
    int row = 16 * w + 2 * (Q) + rhalf;                                        \
    bool ok = (iblk * 64 + row) < NIN_ && (tbase + 2 * c2) < T_;               \
    const float* rp = base + (size_t)row * T_ + tbase + 2 * c2;                \
    float2 v = ok ? *(const float2*)rp : make_float2(0.f, 0.f);                \
    unsigned long long be = __ballot(v.x != 0.f);                              \
    unsigned long long bo = __ballot(v.y != 0.f);                              \
    if (lane == 0) {                                                           \
      evens[16 * w + 2 * (Q)] = (unsigned)be;                                  \
      odds[16 * w + 2 * (Q)] = (unsigned)bo;                                   \
    }                                                                          \
    if (lane == 1) {                                                           \
      evens[16 * w + 2 * (Q) + 1] = (unsigned)(be >> 32);                      \
      odds[16 * w + 2 * (Q) + 1] = (unsigned)(bo >> 32);                       \
    }                                                                          \
  }
    PH1_(0) PH1_(1) PH1_(2) PH1_(3) PH1_(4) PH1_(5) PH1_(6) PH1_(7)
#undef PH1_
    __syncthreads();
    unsigned ev = evens[lane], od = odds[lane];
    unsigned long long* mrow =
        msk + ((size_t)b * T_ + tbase + w * 16) * MW + iblk;
#define BAL_(P)                                                                \
  {                                                                            \
    unsigned sel = ((P) & 1) ? od : ev;                                        \
    unsigned long long bw_ =                                                   \
        __ballot(((sel >> (w * 8 + ((P) >> 1))) & 1u) != 0u);                  \
    if (lane == (P) && (tbase + w * 16 + (P)) < T_)                            \
      mrow[(size_t)(P) * MW] = bw_;                                            \
  }
    BAL_(0)  BAL_(1)  BAL_(2)  BAL_(3)  BAL_(4)  BAL_(5)  BAL_(6)  BAL_(7)
    BAL_(8)  BAL_(9)  BAL_(10) BAL_(11) BAL_(12) BAL_(13) BAL_(14) BAL_(15)
#undef BAL_
    __syncthreads();
  }
}

// ------------- sparse accumulate: Z1[b][t][o] = sum_{active i, ascending} W1T[i][o] -------------
// One 64-thread block per (b,t,o-half-of-256). float4 gathers (1 KB/wave-inst),
// unroll 16 for outstanding-load depth. Each output column sums in strict
// ascending-i serial order -> bit-identical to prior rounds.
__global__ __launch_bounds__(64) void accum1_k(const unsigned long long* __restrict__ msk,
                                               const float* __restrict__ WT,
                                               float* __restrict__ Z1) {
  __shared__ unsigned short list[MAXA2];
  int id = blockIdx.x;
  int bt = id >> 1, oc = id & 1;
  int lane = threadIdx.x;
  unsigned long long wm = (lane < NIB) ? msk[(size_t)bt * MW + lane] : 0ull;
  int pc = __popcll(wm);
  int pre = pc;
#pragma unroll
  for (int d = 1; d < 64; d <<= 1) {
    int o = __shfl_up(pre, d);
    if (lane >= d) pre += o;
  }
  int base = pre - pc;                  // exclusive prefix
  int n = __shfl(pre, 63);              // total actives
  while (wm) {
    int j = __builtin_ctzll(wm);
    if (base < MAXA2) list[base] = (unsigned short)(lane * 64 + j);
    ++base;
    wm &= wm - 1;
  }
  __syncthreads();
  if (n > MAXA2) n = MAXA2;
  const float4* wbase = (const float4*)WT + (size_t)oc * 64 + lane;  // float4 units
  float4 acc = make_float4(0.f, 0.f, 0.f, 0.f);
#pragma unroll 16
  for (int j = 0; j < n; ++j) {
    float4 v = wbase[(size_t)list[j] * (NHID_ / 4)];
    acc.x += v.x;                       // strict ascending-i order per output column
    acc.y += v.y;
    acc.z += v.z;
    acc.w += v.w;
  }
  ((float4*)(Z1 + (size_t)bt * NHID_))[(size_t)oc * 64 + lane] = acc;
}

// ------------- layer-1 scan: truncated-PSP dual IIR (fp64) + refractory (fp32) -------------
__global__ __launch_bounds__(64) void scan1_k(const float* __restrict__ Z1,
                                              unsigned long long* __restrict__ mask) {
  int lane = threadIdx.x;
  int b = blockIdx.x >> 3, g = blockIdx.x & 7;
  int h = g * 64 + lane;
  const double dp   = exp(-0.1);            // PSP decay per step
  const double Ap   = exp(1.0) / 10.0;      // kernel scale (e/tau) x Ts
  const double D77  = exp(-7.7);            // dp^77
  const float  Dref = (float)exp(-1.0);
  const float  Cref = (float)(-20.0 * exp(1.0));  // -SCALE_REF*THETA*e*Ts/TAU_REF
  double Xc = 0.0, Yc = 0.0, Xd = 0.0, Yd = 0.0;
  float xr = 0.f, yr = 0.f;
  const float* zb = Z1 + (size_t)b * T_ * NHID_ + h;
  unsigned long long* mb = mask + (size_t)b * T_ * 8 + g;
  for (int t0 = 0; t0 < T_; t0 += 16) {
    float z[16], zd[16];
#pragma unroll
    for (int k = 0; k < 16; ++k) {
      int t = t0 + k;
      z[k]  = (t < T_) ? zb[(size_t)t * NHID_] : 0.f;
      zd[k] = (t >= KLEN && t < T_) ? zb[(size_t)(t - KLEN) * NHID_] : 0.f;
    }
#pragma unroll
    for (int k = 0; k < 16; ++k) {
      int t = t0 + k;
      if (t >= T_) break;                 // uniform
      Yc = dp * (Yc + Xc); Xc = dp * Xc + (double)z[k];
      Yd = dp * (Yd + Xd); Xd = dp * Xd + (double)zd[k];
      float p = (float)(Ap * (Yc - D77 * (Yd + 77.0 * Xd)));
      yr = Dref * (yr + xr);
      float u = p + Cref * yr;
      float s = (u >= 10.0f) ? 1.0f : 0.0f;
      xr = Dref * xr + s;
      unsigned long long bw = __ballot(u >= 10.0f);
      if (lane == 0) mb[(size_t)t * 8] = bw;
    }
  }
}

// ------------- layer-2 GEMM via spike bitmask: Z2[b][o][t] = sum_{h set, ascending} W2[o][h] -------------
__global__ __launch_bounds__(256) void z2_k(const unsigned long long* __restrict__ mask,
                                            const float* __restrict__ W2,
                                            float* __restrict__ Z2) {
  int wave = blockIdx.x * 4 + (threadIdx.x >> 6);
  int lane = threadIdx.x & 63;
  if (wave >= B_ * T_) return;
  int b = wave / T_, t = wave - b * T_;
  const unsigned long long* m = mask + (size_t)wave * 8;
  if (lane < NOUT_) {
    const float* wr = W2 + (size_t)lane * NHID_;
    float acc = 0.f;
#pragma unroll
    for (int w = 0; w < 8; ++w) {
      unsigned long long mm = m[w];
      while (mm) {
        int j = __builtin_ctzll(mm);
        mm &= mm - 1;
        acc += wr[w * 64 + j];
      }
    }
    Z2[((size_t)b * NOUT_ + lane) * T_ + t] = acc;
  }
}

// ------------- layer-2 scan -> output spikes (16-deep prefetch) -------------
__global__ __launch_bounds__(64) void scan2_k(const float* __restrict__ Z2,
                                              float* __restrict__ out) {
  int n = blockIdx.x * 64 + threadIdx.x;    // n = b*NOUT + o
  if (n >= B_ * NOUT_) return;
  const double dp   = exp(-0.1);
  const double Ap   = exp(1.0) / 10.0;
  const double D77  = exp(-7.7);
  const float  Dref = (float)exp(-1.0);
  const float  Cref = (float)(-20.0 * exp(1.0));
  double Xc = 0.0, Yc = 0.0, Xd = 0.0, Yd = 0.0;
  float xr = 0.f, yr = 0.f;
  const float* row = Z2 + (size_t)n * T_;
  float* orow = out + (size_t)n * T_;
  for (int t0 = 0; t0 < T_; t0 += 16) {
    float z[16], zd[16];
#pragma unroll
    for (int k = 0; k < 16; ++k) {
      int t = t0 + k;
      z[k]  = (t < T_) ? row[t] : 0.f;
      zd[k] = (t >= KLEN && t < T_) ? row[t - KLEN] : 0.f;
    }
#pragma unroll
    for (int k = 0; k < 16; ++k) {
      int t = t0 + k;
      if (t >= T_) break;                 // uniform
      Yc = dp * (Yc + Xc); Xc = dp * Xc + (double)z[k];
      Yd = dp * (Yd + Xd); Xd = dp * Xd + (double)zd[k];
      float p = (float)(Ap * (Yc - D77 * (Yd + 77.0 * Xd)));
      yr = Dref * (yr + xr);
      float u = p + Cref * yr;
      float s = (u >= 10.0f) ? 1.0f : 0.0f;
      xr = Dref * xr + s;
      orow[t] = s;   // spk / Ts, Ts = 1
    }
  }
}

extern "C" void kernel_launch(void* const* d_in, const int* in_sizes, int n_in,
                              void* d_out, int out_size, void* d_ws, size_t ws_size,
                              hipStream_t stream) {
  const float* X  = (const float*)d_in[0];  // (32, 2312, 350)
  const float* W1 = (const float*)d_in[1];  // (512, 2312)
  const float* W2 = (const float*)d_in[2];  // (10, 512)
  float* out = (float*)d_out;               // (32, 10, 350)

  char* ws = (char*)d_ws;
  size_t off = 0;
  float* W1T = (float*)(ws + off);                 off += (size_t)NIN_ * NHID_ * 4;         // 4.73 MB
  unsigned long long* msk = (unsigned long long*)(ws + off); off += (size_t)B_ * T_ * MW * 8; // 3.58 MB
  float* Z1 = (float*)(ws + off);                  off += (size_t)B_ * T_ * NHID_ * 4;      // 22.9 MB
  unsigned long long* mask = (unsigned long long*)(ws + off); off += (size_t)B_ * T_ * 8 * 8; // 0.72 MB
  float* Z2 = (float*)(ws + off);                  off += (size_t)B_ * NOUT_ * T_ * 4;      // 0.45 MB
  if (off > ws_size) return;  // workspace too small -> fail loudly (no launches)

  w1t_k<<<dim3((NIN_ + 31) / 32, NHID_ / 32), dim3(32, 8), 0, stream>>>(W1, W1T);
  inmask_k<<<B_ * NIB, 256, 0, stream>>>(X, msk);
  accum1_k<<<B_ * T_ * 2, 64, 0, stream>>>(msk, W1T, Z1);
  scan1_k<<<B_ * 8, 64, 0, stream>>>(Z1, mask);
  z2_k<<<(B_ * T_ + 3) / 4, 256, 0, stream>>>(mask, W2, Z2);
  scan2_k<<<(B_ * NOUT_ + 63) / 64, 64, 0, stream>>>(Z2, out);
}